// Round 5
// baseline (188.805 us; speedup 1.0000x reference)
//
#include <hip/hip_runtime.h>
#include <math.h>

#define SCALE_L2E 0.51006972157f   // (1/sqrt(8)) * log2(e) -- softmax done in exp2 domain
#define EPSV 1e-5f

typedef __attribute__((ext_vector_type(8))) short bf16x8;
typedef __attribute__((ext_vector_type(4))) float f32x4;
typedef __attribute__((ext_vector_type(16))) float f32x16;
typedef __attribute__((ext_vector_type(4))) int i32x4;
typedef __attribute__((ext_vector_type(2))) int i32x2;

static __device__ __forceinline__ unsigned short bfh(float f) {
    return (unsigned short)(__builtin_bit_cast(unsigned int, f) >> 16);
}
static __device__ __forceinline__ int pack2(float lo, float hi) {
    return __builtin_amdgcn_perm(__builtin_bit_cast(unsigned int, hi),
                                 __builtin_bit_cast(unsigned int, lo), 0x07060302u);
}
#define LGKM0() __asm__ __volatile__("s_waitcnt lgkmcnt(0)" ::: "memory")

// ws layout: [0,8192) ushort wqk B-frags; [8192,40960) ushort W2ᵀ B-frags;
//            byte 81920: float bnA[64], bnB[64]
__global__ void prep_kernel(const float* __restrict__ w_qk,
                            const float* __restrict__ conv_w,
                            const float* __restrict__ conv_b,
                            const float* __restrict__ bn_g, const float* __restrict__ bn_b,
                            const float* __restrict__ bn_m, const float* __restrict__ bn_v,
                            unsigned short* __restrict__ ws) {
    int i = blockIdx.x * 256 + threadIdx.x;
    if (i < 8192) {
        // qk B-frag: frag(nt,ks): val = w_qk[k][n], k=ks*32+(l>>4)*8+j, n=nt*16+(l&15)
        int f = i >> 9, rem = i & 511, l = rem >> 3, j = rem & 7;
        int nt = f >> 1, ks = f & 1;
        int k = ks * 32 + (l >> 4) * 8 + j;
        int nn = nt * 16 + (l & 15);
        ws[i] = bfh(w_qk[k * 128 + nn]);
    } else if (i < 40960) {
        // W2ᵀ B-frag: frag(h,nt,ks): val = conv_w[h][o][c], c=ks*32+(l>>4)*8+j, o=nt*16+(l&15)
        int i2 = i - 8192;
        int g = i2 >> 9, rem = i2 & 511, l = rem >> 3, j = rem & 7;
        int h = g >> 3, nt = (g >> 1) & 3, ks = g & 1;
        int c = ks * 32 + (l >> 4) * 8 + j;
        int o = nt * 16 + (l & 15);
        ws[i] = bfh(conv_w[h * 4096 + o * 64 + c]);
    } else if (i < 41024) {
        int o = i - 40960;
        float gv = bn_g[o] * rsqrtf(bn_v[o] + EPSV);
        float bb = bn_b[o] - bn_m[o] * gv;
        float cb = 0.f;
        for (int h = 0; h < 8; h++) cb += conv_b[h * 64 + o];
        float* wsf = (float*)(ws + 40960);
        wsf[o] = gv;
        wsf[64 + o] = bb + cb * gv;
    }
}

// One WAVE per (n,t) tile; 4 waves/block; NO __syncthreads (all LDS is wave-private).
// Per-wave LDS 9216 B (block 36864 B -> 4 blocks/CU, same as VGPR cap):
//   region A [0,4096):    qbuf[32][24]@0 + kbuf[32][24]@1536  (qk->dots)
//                         then FWT swizzled [64 rows][64 B]   (per-hh FW staging)
//   region B [4096,9216): P0 [32][40]u16 @+0, P1 @+2560 (stride 80 B, b128-aligned)
// SWAPPED DOTS (r5): dots = mfma(A=K, B=Q) -> lane r32 holds softmax row u=r32
// in 16 regs (v-halves split across lane^32). Softmax fully in-register (all 64
// lanes), Gh buffer + 2 LDS round trips per hp eliminated. 3 lgkm waits/hp vs 5.
// VGPR cap vs spill/occupancy (MEASURED r0-r4):
//   cap 48: heavy spill 174us | cap 64: spill 108us | cap 80/128: no spill, 98us
//   occupancy follows the VGPR quantum (steps at 64/128): 80..128 identical.
//   (256,2)=cap 128. Spill tripwire: FETCH > 70 MB. Do NOT tighten.
__global__ __launch_bounds__(256, 2)
void sagc_kernel(const float* __restrict__ x,
                 const float* __restrict__ ln_g, const float* __restrict__ ln_b,
                 const float* __restrict__ b_qk,
                 const float* __restrict__ topo,
                 const unsigned short* __restrict__ ws,
                 float* __restrict__ out)
{
    __shared__ __align__(16) unsigned char smem[36864];
    const int tid = threadIdx.x;
    const int lane = tid & 63, wv = tid >> 6;
    const int l15 = lane & 15, quad = lane >> 4;
    const int r32 = lane & 31, hi = lane >> 5;

    unsigned char* my = smem + wv * 9216;
    unsigned short* qbuf = (unsigned short*)my;            // [32][24] u16
    unsigned short* kbuf = (unsigned short*)(my + 1536);   // [32][24] u16
    unsigned char*  fwb  = my;                             // FWT swizzled, 4096 B
    unsigned char*  pb0  = my + 4096;                      // P0 [32][40] u16
    unsigned char*  pb1  = my + 4096 + 2560;               // P1

    const unsigned short* wqk = ws;
    const unsigned short* w2f = ws + 8192;
    const float* bnA = (const float*)(ws + 40960);
    const float* bnB = bnA + 64;

    const int tile = blockIdx.x * 4 + wv;
    const int n = tile >> 8, t = tile & 255;
    const float* xg = x + (size_t)n * 409600 + (size_t)t * 25;   // + c*6400 + v
    float* og = out + (size_t)n * 409600 + (size_t)t * 25;

    // ---- direct-register x load (no LDS staging): xf[mt][ks][j] = x[c][v], 0 at v>=25 ----
    float xf[2][2][8];
    #pragma unroll
    for (int mt = 0; mt < 2; mt++) {
        const int v = mt * 16 + l15;
        const bool ok = (v < 25);
        const float* xc = xg + v;
        #pragma unroll
        for (int ks = 0; ks < 2; ks++)
            #pragma unroll
            for (int j = 0; j < 8; j++) {
                int c = ks * 32 + quad * 8 + j;
                xf[mt][ks][j] = ok ? xc[c * 6400] : 0.f;
            }
    }

    // ---- pack x A-frags; accumulate per-row sums for LN stats ----
    bf16x8 xa[2][2];
    float sum_[2] = {0.f, 0.f}, ssq_[2] = {0.f, 0.f};
    #pragma unroll
    for (int mt = 0; mt < 2; mt++)
        #pragma unroll
        for (int ks = 0; ks < 2; ks++) {
            i32x4 pa;
            #pragma unroll
            for (int q = 0; q < 4; q++)
                pa[q] = pack2(xf[mt][ks][2 * q], xf[mt][ks][2 * q + 1]);
            xa[mt][ks] = __builtin_bit_cast(bf16x8, pa);
            #pragma unroll
            for (int j = 0; j < 8; j++) {
                float a = xf[mt][ks][j];
                sum_[mt] += a;
                ssq_[mt] += a * a;
            }
        }

    // ---- LN stats via cross-quad shuffle reduce ----
    float muv[2], rsv[2];
    #pragma unroll
    for (int mt = 0; mt < 2; mt++) {
        sum_[mt] += __shfl_xor(sum_[mt], 16);
        sum_[mt] += __shfl_xor(sum_[mt], 32);
        ssq_[mt] += __shfl_xor(ssq_[mt], 16);
        ssq_[mt] += __shfl_xor(ssq_[mt], 32);
        muv[mt] = sum_[mt] * 0.015625f;
        rsv[mt] = rsqrtf(ssq_[mt] * 0.015625f - muv[mt] * muv[mt] + EPSV);
    }

    // ---- normalize in-register -> yn A-frags ----
    bf16x8 yna[2][2];
    #pragma unroll
    for (int ks = 0; ks < 2; ks++) {
        f32x4 ga = *(const f32x4*)&ln_g[ks * 32 + quad * 8];
        f32x4 gb = *(const f32x4*)&ln_g[ks * 32 + quad * 8 + 4];
        f32x4 ba = *(const f32x4*)&ln_b[ks * 32 + quad * 8];
        f32x4 bb = *(const f32x4*)&ln_b[ks * 32 + quad * 8 + 4];
        #pragma unroll
        for (int mt = 0; mt < 2; mt++) {
            float yv[8];
            #pragma unroll
            for (int j = 0; j < 8; j++) {
                float g = (j < 4) ? ga[j] : gb[j - 4];
                float bt = (j < 4) ? ba[j] : bb[j - 4];
                yv[j] = (xf[mt][ks][j] - muv[mt]) * rsv[mt] * g + bt;
            }
            i32x4 p;
            #pragma unroll
            for (int q = 0; q < 4; q++) p[q] = pack2(yv[2 * q], yv[2 * q + 1]);
            yna[mt][ks] = __builtin_bit_cast(bf16x8, p);
        }
    }

    // ---- accumulators ----
    f32x4 acc[2][4];
    #pragma unroll
    for (int mt = 0; mt < 2; mt++)
        #pragma unroll
        for (int nt = 0; nt < 4; nt++)
            acc[mt][nt] = (f32x4){0.f, 0.f, 0.f, 0.f};

    const f32x4 z4 = {0.f, 0.f, 0.f, 0.f};
    const bf16x8 z8 = {0, 0, 0, 0, 0, 0, 0, 0};

    // FWT swizzle constants (unchanged; 16B block ^= (l15>>2)&3)
    const int sw4 = (l15 >> 2) & 3;
    unsigned char* w0p = fwb + ((((quad >> 1) ^ sw4)) << 4) + (quad & 1) * 8;
    unsigned char* w1p = fwb + (((((quad >> 1) ^ sw4)) ^ 2) << 4) + (quad & 1) * 8;
    unsigned char* brp = fwb + l15 * 64 + ((quad ^ sw4) << 4);

    // topo gather base row (clamped for lanes u>=25; their results are discarded)
    const int uc = (r32 < 25) ? r32 : 24;

    // in-register softmax + P store. dd: lane r32 = row u; v(r) = (r&3)+8*(r>>2)+4*hi.
    auto softmax_store = [&](f32x16& dd, const float* tp, unsigned char* Pb) {
        // mask v>=25 to -3e30 (exp2 underflows to exact 0)
        dd[12] = hi ? -3e30f : dd[12];
        dd[13] = -3e30f; dd[14] = -3e30f; dd[15] = -3e30f;
        float t8[8];
        #pragma unroll
        for (int r = 0; r < 8; r++) t8[r] = fmaxf(dd[r], dd[r + 8]);
        #pragma unroll
        for (int r = 0; r < 4; r++) t8[r] = fmaxf(t8[r], t8[r + 4]);
        float m = fmaxf(fmaxf(t8[0], t8[1]), fmaxf(t8[2], t8[3]));
        m = fmaxf(m, __shfl_xor(m, 32));
        float s0 = 0.f, s1 = 0.f, s2 = 0.f, s3 = 0.f;
        #pragma unroll
        for (int r = 0; r < 16; r += 4) {
            dd[r]     = __builtin_amdgcn_exp2f(dd[r] - m);     s0 += dd[r];
            dd[r + 1] = __builtin_amdgcn_exp2f(dd[r + 1] - m); s1 += dd[r + 1];
            dd[r + 2] = __builtin_amdgcn_exp2f(dd[r + 2] - m); s2 += dd[r + 2];
            dd[r + 3] = __builtin_amdgcn_exp2f(dd[r + 3] - m); s3 += dd[r + 3];
        }
        float s = (s0 + s1) + (s2 + s3);
        s += __shfl_xor(s, 32);
        float inv = __builtin_amdgcn_rcpf(s);
        #pragma unroll
        for (int r = 0; r < 16; r++) dd[r] = dd[r] * inv * tp[r];
        if (r32 < 25) {
            unsigned char* rowp = Pb + r32 * 80 + hi * 8;
            *(i32x2*)(rowp +  0) = (i32x2){pack2(dd[0], dd[1]),   pack2(dd[2], dd[3])};
            *(i32x2*)(rowp + 16) = (i32x2){pack2(dd[4], dd[5]),   pack2(dd[6], dd[7])};
            *(i32x2*)(rowp + 32) = (i32x2){pack2(dd[8], dd[9]),   pack2(dd[10], dd[11])};
            *(i32x2*)(rowp + 48) = (i32x2){pack2(dd[12], dd[13]), pack2(dd[14], dd[15])};
        }
    };

    const f32x16 z16 = {0.f,0.f,0.f,0.f,0.f,0.f,0.f,0.f,0.f,0.f,0.f,0.f,0.f,0.f,0.f,0.f};

    // ---- head-pair loop ----
    #pragma unroll
    for (int hp = 0; hp < 4; hp++) {
        // qk tiles: q-tile nt=hp (SCALE*log2e folded), k-tile nt=4+hp
        #pragma unroll
        for (int tsel = 0; tsel < 2; tsel++) {
            int nt = tsel ? (4 + hp) : hp;
            bf16x8 b0 = *(const bf16x8*)&wqk[(nt * 2 + 0) * 512 + lane * 8];
            bf16x8 b1 = *(const bf16x8*)&wqk[(nt * 2 + 1) * 512 + lane * 8];
            float bias = b_qk[(tsel ? 64 : 0) + hp * 16 + l15];
            unsigned short* buf = tsel ? kbuf : qbuf;
            #pragma unroll
            for (int mt = 0; mt < 2; mt++) {
                f32x4 d = __builtin_amdgcn_mfma_f32_16x16x32_bf16(yna[mt][0], b0, z4, 0, 0, 0);
                d = __builtin_amdgcn_mfma_f32_16x16x32_bf16(yna[mt][1], b1, d, 0, 0, 0);
                #pragma unroll
                for (int r = 0; r < 4; r++) {
                    int u = mt * 16 + quad * 4 + r;
                    if (u < 25) {
                        float val = d[r] + bias;
                        if (!tsel) val *= SCALE_L2E;
                        buf[u * 24 + l15] = bfh(val);
                    }
                }
            }
        }

        // topo gather hh=0 (16 imm-offset dword loads; in flight across the wait)
        float tp0[16];
        {
            const float* tb = topo + (hp * 2 + 0) * 625 + uc * 25 + hi * 4;
            #pragma unroll
            for (int r = 0; r < 16; r++) {
                int off = (r < 12) ? ((r & 3) + (r >> 2) * 8)
                        : (r == 12 ? (hi ? 0 : 24) : 0);   // pad offsets clamped in-bounds
                tp0[r] = tb[off];
            }
        }
        LGKM0();   // q/k visible

        // dots hh=0 SWAPPED: A=K, B=Q -> dd[r] = dots[u=r32][v(r)]
        f32x16 p0;
        {
            bf16x8 ak = z8, bq = z8;
            if (hi == 0) {
                ak = *(const bf16x8*)&kbuf[r32 * 24 + 0];
                bq = *(const bf16x8*)&qbuf[r32 * 24 + 0];
            }
            p0 = __builtin_amdgcn_mfma_f32_32x32x16_bf16(ak, bq, z16, 0, 0, 0);
        }
        // topo gather hh=1 (issued under softmax0)
        float tp1[16];
        {
            const float* tb = topo + (hp * 2 + 1) * 625 + uc * 25 + hi * 4;
            #pragma unroll
            for (int r = 0; r < 16; r++) {
                int off = (r < 12) ? ((r & 3) + (r >> 2) * 8)
                        : (r == 12 ? (hi ? 0 : 24) : 0);
                tp1[r] = tb[off];
            }
        }
        // dots hh=1
        f32x16 p1;
        {
            bf16x8 ak = z8, bq = z8;
            if (hi == 0) {
                ak = *(const bf16x8*)&kbuf[r32 * 24 + 8];
                bq = *(const bf16x8*)&qbuf[r32 * 24 + 8];
            }
            p1 = __builtin_amdgcn_mfma_f32_32x32x16_bf16(ak, bq, z16, 0, 0, 0);
        }

        softmax_store(p0, tp0, pb0);
        softmax_store(p1, tp1, pb1);

        // W2^T frags hh=0 (vmcnt; L2-hot)
        bf16x8 w2e[8];
        #pragma unroll
        for (int nt = 0; nt < 4; nt++) {
            int h = hp * 2;
            w2e[2 * nt]     = *(const bf16x8*)&w2f[((h * 4 + nt) * 2 + 0) * 512 + lane * 8];
            w2e[2 * nt + 1] = *(const bf16x8*)&w2f[((h * 4 + nt) * 2 + 1) * 512 + lane * 8];
        }

        // FW hh=0 (FWT overwrites q/k region; same-wave DS order keeps it after dots reads)
        #pragma unroll
        for (int nt = 0; nt < 4; nt++) {
            f32x4 dw0 = __builtin_amdgcn_mfma_f32_16x16x32_bf16(xa[0][0], w2e[2 * nt], z4, 0, 0, 0);
            dw0 = __builtin_amdgcn_mfma_f32_16x16x32_bf16(xa[0][1], w2e[2 * nt + 1], dw0, 0, 0, 0);
            f32x4 dw1 = __builtin_amdgcn_mfma_f32_16x16x32_bf16(xa[1][0], w2e[2 * nt], z4, 0, 0, 0);
            dw1 = __builtin_amdgcn_mfma_f32_16x16x32_bf16(xa[1][1], w2e[2 * nt + 1], dw1, 0, 0, 0);
            i32x2 q0 = {pack2(dw0[0], dw0[1]), pack2(dw0[2], dw0[3])};
            i32x2 q1 = {pack2(dw1[0], dw1[1]), pack2(dw1[2], dw1[3])};
            *(i32x2*)(w0p + nt * 1024 + l15 * 64) = q0;
            *(i32x2*)(w1p + nt * 1024 + l15 * 64) = q1;
        }
        // W2^T frags hh=1 (hides under the wait + PV0)
        bf16x8 w2o[8];
        #pragma unroll
        for (int nt = 0; nt < 4; nt++) {
            int h = hp * 2 + 1;
            w2o[2 * nt]     = *(const bf16x8*)&w2f[((h * 4 + nt) * 2 + 0) * 512 + lane * 8];
            w2o[2 * nt + 1] = *(const bf16x8*)&w2f[((h * 4 + nt) * 2 + 1) * 512 + lane * 8];
        }
        LGKM0();   // P0/P1 + FWT(hh=0) visible

        // PV hh=0: acc += P0 @ FW0
        {
            bf16x8 ag0 = *(const bf16x8*)(pb0 + l15 * 80 + quad * 16);
            bf16x8 ag1 = *(const bf16x8*)(pb0 + (16 + l15) * 80 + quad * 16);
            #pragma unroll
            for (int nt = 0; nt < 4; nt++) {
                bf16x8 br = *(const bf16x8*)(brp + nt * 1024);
                acc[0][nt] = __builtin_amdgcn_mfma_f32_16x16x32_bf16(ag0, br, acc[0][nt], 0, 0, 0);
                acc[1][nt] = __builtin_amdgcn_mfma_f32_16x16x32_bf16(ag1, br, acc[1][nt], 0, 0, 0);
            }
        }

        // FW hh=1 -> FWT (after PV0's reads; same-wave DS ordering)
        #pragma unroll
        for (int nt = 0; nt < 4; nt++) {
            f32x4 dw0 = __builtin_amdgcn_mfma_f32_16x16x32_bf16(xa[0][0], w2o[2 * nt], z4, 0, 0, 0);
            dw0 = __builtin_amdgcn_mfma_f32_16x16x32_bf16(xa[0][1], w2o[2 * nt + 1], dw0, 0, 0, 0);
            f32x4 dw1 = __builtin_amdgcn_mfma_f32_16x16x32_bf16(xa[1][0], w2o[2 * nt], z4, 0, 0, 0);
            dw1 = __builtin_amdgcn_mfma_f32_16x16x32_bf16(xa[1][1], w2o[2 * nt + 1], dw1, 0, 0, 0);
            i32x2 q0 = {pack2(dw0[0], dw0[1]), pack2(dw0[2], dw0[3])};
            i32x2 q1 = {pack2(dw1[0], dw1[1]), pack2(dw1[2], dw1[3])};
            *(i32x2*)(w0p + nt * 1024 + l15 * 64) = q0;
            *(i32x2*)(w1p + nt * 1024 + l15 * 64) = q1;
        }
        LGKM0();   // FWT(hh=1) visible

        // PV hh=1: acc += P1 @ FW1
        {
            bf16x8 ag0 = *(const bf16x8*)(pb1 + l15 * 80 + quad * 16);
            bf16x8 ag1 = *(const bf16x8*)(pb1 + (16 + l15) * 80 + quad * 16);
            #pragma unroll
            for (int nt = 0; nt < 4; nt++) {
                bf16x8 br = *(const bf16x8*)(brp + nt * 1024);
                acc[0][nt] = __builtin_amdgcn_mfma_f32_16x16x32_bf16(ag0, br, acc[0][nt], 0, 0, 0);
                acc[1][nt] = __builtin_amdgcn_mfma_f32_16x16x32_bf16(ag1, br, acc[1][nt], 0, 0, 0);
            }
        }
    }

    // ---- epilogue: BN + residual + ReLU, direct global store ----
    #pragma unroll
    for (int nt = 0; nt < 4; nt++) {
        int o = nt * 16 + l15;
        float gA = bnA[o], gB = bnB[o];
        #pragma unroll
        for (int mt = 0; mt < 2; mt++) {
            int ub = mt * 16 + quad * 4;
            #pragma unroll
            for (int r = 0; r < 4; r++) {
                int u = ub + r;
                if (u < 25) {
                    float val = acc[mt][nt][r] * gA + gB + xg[o * 6400 + u];
                    og[o * 6400 + u] = fmaxf(val, 0.f);
                }
            }
        }
    }
}

extern "C" void kernel_launch(void* const* d_in, const int* in_sizes, int n_in,
                              void* d_out, int out_size, void* d_ws, size_t ws_size,
                              hipStream_t stream) {
    const float* x      = (const float*)d_in[0];
    const float* ln_g   = (const float*)d_in[1];
    const float* ln_b   = (const float*)d_in[2];
    const float* w_qk   = (const float*)d_in[3];
    const float* b_qk   = (const float*)d_in[4];
    const float* topo   = (const float*)d_in[5];
    const float* conv_w = (const float*)d_in[6];
    const float* conv_b = (const float*)d_in[7];
    const float* bn_g   = (const float*)d_in[8];
    const float* bn_b   = (const float*)d_in[9];
    const float* bn_m   = (const float*)d_in[10];
    const float* bn_v   = (const float*)d_in[11];
    float* outp = (float*)d_out;
    unsigned short* wsp = (unsigned short*)d_ws;

    hipLaunchKernelGGL(prep_kernel, dim3(161), dim3(256), 0, stream,
                       w_qk, conv_w, conv_b, bn_g, bn_b, bn_m, bn_v, wsp);
    hipLaunchKernelGGL(sagc_kernel, dim3(2048), dim3(256), 0, stream,
                       x, ln_g, ln_b, b_qk, topo, (const unsigned short*)wsp, outp);
}